// Round 11
// baseline (194.021 us; speedup 1.0000x reference)
//
#include <hip/hip_runtime.h>
#include <hip/hip_bf16.h>

// Locally-connected conv, ALL FP32 in/out, bf16 MFMA compute.
//   x:   (32, 16, 64, 64)        float
//   w:   (60, 60, 16, 5, 5, 16)  float   (per-position 400x16, k innermost)
//   out: (32, 16, 60, 60)        float
//
// Round-11: barrier-free, LDS-free W consumption. Key fact: with
// k_r=(uv,c) ordering, B-frag element = w[(c0+jj)*25+uvB][l15]; for fixed
// (q,jj) the 16 l15-lanes consume one full 64B line -> one wave B-load =
// 4 fully-dense lines. W goes global->register directly (8 dword loads +
// v_cvt_pk per chunk), no LDS, no __syncthreads, nothing to drain.
// (r6-r10 lesson: every LDS+vmcnt(0)-barrier W path plateaus at 48-74 us
// for a 14.6 us stream; r9 lesson: never materialize W transformed.)
//  * lc_direct: 1 wave/position (r9-proven launch shape), A-frags from
//    r5-r8-proven xc[b][h][w][c], 26 MFMA, packed ws store.
//  * make_xc + transpose_out proven unchanged.

#define OUT_HW 60
#define IN_HW  64
#define CIN    16
#define COUT   16
#define NPOS   3600              // OUT_HW*OUT_HW
#define BK     512               // NB*COUT
#define BSTR   65536             // xc b-stride: IN_HW*IN_HW*CIN
#define XC_ELE (32u * 64u * 64u * 16u)   // 2,097,152 bf16 elements

typedef __attribute__((ext_vector_type(8))) short bf16x8;
typedef __attribute__((ext_vector_type(4))) float f32x4;

static __device__ __forceinline__ unsigned pk2(float a, float b) {
    union { __hip_bfloat162 h; unsigned u; } cv;
    cv.h = __float22bfloat162_rn(make_float2(a, b));
    return cv.u;
}

// ---- prepass: xc[b][h][w][c] bf16 <- x[b][c][h][w] fp32 (proven r5-r8) ----
__global__ __launch_bounds__(256)
void make_xc(const float* __restrict__ x, ushort* __restrict__ xc) {
    const int bh = blockIdx.x;               // b*64 + h
    const int b = bh >> 6, h = bh & 63;
    const int t = threadIdx.x;
    const int cq = t & 3, wc = t >> 2;
    const float* src = x + ((size_t)(b * CIN) * IN_HW + h) * IN_HW + wc;
    float f[4];
#pragma unroll
    for (int e = 0; e < 4; ++e)
        f[e] = src[(size_t)(cq * 4 + e) * (IN_HW * IN_HW)];
    union { ushort4 v; unsigned u[2]; } o;
    o.u[0] = pk2(f[0], f[1]);
    o.u[1] = pk2(f[2], f[3]);
    *(ushort4*)&xc[((size_t)bh * IN_HW + wc) * CIN + cq * 4] = o.v;
}

// ---- main: one wave per position; no LDS, no barriers, W direct ----
__global__ __launch_bounds__(64)
void lc_direct(const ushort* __restrict__ xc, const float* __restrict__ w,
               float* __restrict__ dst) {
    const int bid = blockIdx.x;
    const int pos = (bid & 7) * 450 + (bid >> 3);   // XCD swizzle (bijective)
    const int i = pos / OUT_HW, j = pos - i * OUT_HW;
    const int lane = threadIdx.x;
    const int l15 = lane & 15, q = lane >> 4;
    const int qh = q >> 1, c0 = (q & 1) << 3;

    // per-lane W base: addr(jj,cc) = wb[(jj*25 + cc*2)*16]
    //   = w[pos][m=(c0+jj)*25+(cc*2+qh)][k=l15]
    const float* wb = w + (size_t)pos * 6400 + (c0 * 25 + qh) * 16 + l15;
    const int base_hw = i * IN_HW + j;
    const ushort* xp0 = xc + (size_t)l15 * BSTR;          // b = l15
    const ushort* xp1 = xp0 + (size_t)16 * BSTR;          // b = l15 + 16

    f32x4 acc0 = {0.f, 0.f, 0.f, 0.f}, acc1 = {0.f, 0.f, 0.f, 0.f};
#pragma unroll
    for (int cc = 0; cc < 13; ++cc) {
        const int uvB = cc * 2 + qh;
        const bool okB = (uvB < 25);                 // only cc=12,qh=1 fails
        // B: 8 dword loads; each wave-instr = 4 fully-dense 64B lines
        float bf[8];
#pragma unroll
        for (int jj = 0; jj < 8; ++jj)
            bf[jj] = okB ? wb[(jj * 25 + cc * 2) * 16] : 0.f;
        union { bf16x8 v; unsigned u[4]; } pb;
#pragma unroll
        for (int jj = 0; jj < 4; ++jj) pb.u[jj] = pk2(bf[2 * jj], bf[2 * jj + 1]);

        // A: contiguous 16B from xc (clamped tap where W==0)
        const int uvA = okB ? uvB : 24;
        const int uA = (uvA * 13) >> 6;              // uv/5 for uv<=24
        const int vA = uvA - 5 * uA;
        const size_t xo = (size_t)(base_hw + uA * IN_HW + vA) * CIN + c0;
        const bf16x8 a0 = *(const bf16x8*)(xp0 + xo);
        const bf16x8 a1 = *(const bf16x8*)(xp1 + xo);

        acc0 = __builtin_amdgcn_mfma_f32_16x16x32_bf16(a0, pb.v, acc0, 0, 0, 0);
        acc1 = __builtin_amdgcn_mfma_f32_16x16x32_bf16(a1, pb.v, acc1, 0, 0, 0);
    }

    // packed ws[pos][bk]: wave writes its full 2 KB block (r9-proven)
#pragma unroll
    for (int r = 0; r < 4; ++r) {
        dst[(size_t)pos * BK + (q * 4 + r) * 16 + l15]      = acc0[r];
        dst[(size_t)pos * BK + (q * 4 + r + 16) * 16 + l15] = acc1[r];
    }
}

// ---- epilogue: ws[oij][bk] -> out[bk][oij] (proven r3..r6) ----
__global__ __launch_bounds__(256)
void transpose_out(const float* __restrict__ src, float* __restrict__ out) {
    __shared__ float tile[64][65];
    const int o0 = blockIdx.x * 64;
    const int k0 = blockIdx.y * 64;
    const int t  = threadIdx.x;
    const int tx = t & 63, ty = t >> 6;
    for (int r = ty; r < 64; r += 4) {
        const int oij = o0 + r;
        if (oij < NPOS) tile[r][tx] = src[(size_t)oij * BK + k0 + tx];
    }
    __syncthreads();
    for (int r = ty; r < 64; r += 4) {
        const int oij = o0 + tx;
        if (oij < NPOS) out[(size_t)(k0 + r) * NPOS + oij] = tile[tx][r];
    }
}

// ---- emergency fallback (ws too small): naive, correct, slow ----
__global__ __launch_bounds__(256)
void lc_naive(const float* __restrict__ x, const float* __restrict__ w,
              float* __restrict__ out) {
    const int gid = blockIdx.x * 256 + threadIdx.x;
    if (gid >= 32 * COUT * NPOS) return;
    const int j = gid % OUT_HW;
    int rest = gid / OUT_HW;
    const int i = rest % OUT_HW; rest /= OUT_HW;
    const int k = rest % COUT;
    const int b = rest / COUT;
    const float* wp = w + (size_t)(i * OUT_HW + j) * 6400 + k;
    float s = 0.f;
    for (int c = 0; c < CIN; ++c)
        for (int u = 0; u < 5; ++u)
            for (int v = 0; v < 5; ++v)
                s += x[((size_t)(b * CIN + c) * IN_HW + i + u) * IN_HW + j + v]
                   * wp[((c * 5 + u) * 5 + v) * COUT];
    out[gid] = s;
}

extern "C" void kernel_launch(void* const* d_in, const int* in_sizes, int n_in,
                              void* d_out, int out_size, void* d_ws, size_t ws_size,
                              hipStream_t stream) {
    const float* x = (const float*)d_in[0];
    const float* w = (const float*)d_in[1];
    float* out = (float*)d_out;

    const size_t xcBytes  = (size_t)XC_ELE * 2;        // 4,194,304
    const size_t outBytes = (size_t)NPOS * BK * 4;     // 7,372,800
    ushort* xc = (ushort*)d_ws;

    if (ws_size >= xcBytes + outBytes) {
        float* wsOut = (float*)((char*)d_ws + xcBytes);
        make_xc<<<32 * IN_HW, 256, 0, stream>>>(x, xc);
        lc_direct<<<NPOS, 64, 0, stream>>>(xc, w, wsOut);
        transpose_out<<<dim3((NPOS + 63) / 64, BK / 64), 256, 0, stream>>>(wsOut, out);
    } else if (ws_size >= xcBytes) {
        make_xc<<<32 * IN_HW, 256, 0, stream>>>(x, xc);
        // scattered-store variant not worth a second kernel: reuse naive path
        lc_naive<<<(32 * COUT * NPOS + 255) / 256, 256, 0, stream>>>(x, w, out);
    } else {
        lc_naive<<<(32 * COUT * NPOS + 255) / 256, 256, 0, stream>>>(x, w, out);
    }
}